// Round 6
// baseline (1512.689 us; speedup 1.0000x reference)
//
#include <hip/hip_runtime.h>
#include <hip/hip_bf16.h>

#define NNODES 100000
#define NEDGES 1600000
#define INF_   128
#define HF     128
#define OUTF   112
#define NLAYERS 4
#define NNETS  3

typedef __attribute__((ext_vector_type(8))) short bf16x8;
typedef __attribute__((ext_vector_type(8))) unsigned short u16x8;
typedef __attribute__((ext_vector_type(4))) float f32x4;
typedef unsigned long long u64;

__device__ __forceinline__ float bf2f(short u){
  unsigned x = ((unsigned)(unsigned short)u) << 16;
  return __builtin_bit_cast(float, x);
}
__device__ __forceinline__ unsigned short f2bf(float f){
  unsigned u = __builtin_bit_cast(unsigned, f);
  u += 0x7fffu + ((u >> 16) & 1u);   // RNE
  return (unsigned short)(u >> 16);
}

// ---------------- int64-vs-int32 edge_index format probe ----------------
__global__ void detect_fmt(const u64* __restrict__ ei64, int* __restrict__ flag){
  u64 v = ei64[threadIdx.x];
  u64 b = __ballot((v >> 32) != 0ull);
  if (threadIdx.x == 0) flag[0] = (b == 0ull) ? 1 : 0;
}

__device__ __forceinline__ int load_dst(const int* ei, int is64, int e){
  return is64 ? ei[2*(NEDGES + e)] : ei[NEDGES + e];
}
__device__ __forceinline__ int load_src(const int* ei, int is64, int e){
  return is64 ? ei[2*e] : ei[e];
}

// ---------------- CSR build ----------------
__global__ void zero_counts(int* counts){
  int i = blockIdx.x*256 + threadIdx.x;
  if (i < NNODES) counts[i] = 0;
}

__global__ void hist_kernel(const int* __restrict__ ei, const int* __restrict__ flag, int* counts){
  int e = blockIdx.x*256 + threadIdx.x;
  if (e < NEDGES){
    int d = load_dst(ei, flag[0], e);
    if ((unsigned)d < NNODES) atomicAdd(&counts[d], 1);
  }
}

__global__ __launch_bounds__(256) void scan1(const int* __restrict__ counts,
                                             int* __restrict__ scanned,
                                             int* __restrict__ partials){
  __shared__ int s[256];
  int t = threadIdx.x, i = blockIdx.x*256 + t;
  int v = (i < NNODES) ? counts[i] : 0;
  s[t] = v; __syncthreads();
  for (int off=1; off<256; off<<=1){
    int a = (t >= off) ? s[t-off] : 0;
    __syncthreads();
    s[t] += a;
    __syncthreads();
  }
  if (i < NNODES) scanned[i] = s[t] - v;
  if (t == 255) partials[blockIdx.x] = s[255];
}

__global__ __launch_bounds__(512) void scan2(int* partials, int G){
  __shared__ int s[512];
  int t = threadIdx.x;
  int v = (t < G) ? partials[t] : 0;
  s[t] = v; __syncthreads();
  for (int off=1; off<512; off<<=1){
    int a = (t >= off) ? s[t-off] : 0;
    __syncthreads();
    s[t] += a;
    __syncthreads();
  }
  if (t < G) partials[t] = s[t] - v;
}

__global__ void scan3(const int* __restrict__ scanned, const int* __restrict__ partials,
                      int* __restrict__ row_ptr, int* __restrict__ cursor){
  int i = blockIdx.x*256 + threadIdx.x;
  if (i < NNODES){
    int v = scanned[i] + partials[i>>8];
    row_ptr[i] = v;
    cursor[i]  = v;
  } else if (i == NNODES){
    row_ptr[NNODES] = NEDGES;
  }
}

__global__ void scatter_kernel(const int* __restrict__ ei, const float* __restrict__ ew,
                               const int* __restrict__ flag,
                               int* cursor, u64* __restrict__ csr_pack){
  int e = blockIdx.x*256 + threadIdx.x;
  if (e < NEDGES){
    int is64 = flag[0];
    int s = load_src(ei, is64, e);
    int d = load_dst(ei, is64, e);
    if ((unsigned)d < NNODES && (unsigned)s < NNODES){
      int pos = atomicAdd(&cursor[d], 1);
      if ((unsigned)pos < NEDGES){
        u64 pk = ((u64)__builtin_bit_cast(unsigned, ew[e]) << 32) | (unsigned)s;
        csr_pack[pos] = pk;
      }
    }
  }
}

// ---------------- weight prep (fp32 -> bf16, transposed to [C][K]) ----------------
__global__ void prep_w(const float* __restrict__ w0, const float* __restrict__ cw,
                       const float* __restrict__ w1,
                       short* __restrict__ w0t, short* __restrict__ cwt, short* __restrict__ w1t){
  int i = blockIdx.x*256 + threadIdx.x;
  const int n0 = NNETS*HF*HF;
  const int n1 = NNETS*NLAYERS*HF*HF;
  const int n2 = NNETS*OUTF*HF;
  if (i < n0){
    int net = i/(HF*HF), r = i%(HF*HF), c = r/HF, k = r%HF;
    w0t[i] = (short)f2bf(w0[(size_t)net*HF*HF + k*HF + c]);
  } else if (i < n0 + n1){
    int j = i - n0;
    int nl = j/(HF*HF), r = j%(HF*HF), c = r/HF, k = r%HF;
    cwt[j] = (short)f2bf(cw[(size_t)nl*HF*HF + k*HF + c]);
  } else if (i < n0 + n1 + n2){
    int j = i - n0 - n1;
    int net = j/(OUTF*HF), r = j%(OUTF*HF), c = r/HF, k = r%HF;
    w1t[j] = (short)f2bf(w1[(size_t)net*HF*OUTF + k*OUTF + c]);
  }
}

// All node-state buffers are interleaved: [node][net][128] bf16.
#define IDX(row,net) (((size_t)(row)*NNETS + (net))*128)

// ---------------- input GEMM: h0 = relu(x @ w0 + b0), x0 = h0, all 3 nets ----------------
__global__ __launch_bounds__(256) void gemm_in(
    const float* __restrict__ x, const short* __restrict__ w0t, const float* __restrict__ b0,
    short* __restrict__ h, short* __restrict__ x0)
{
  __shared__ short As[128*128];
  const int t = threadIdx.x;
  const int rowBase = blockIdx.x * 128;
  #pragma unroll
  for (int it=0; it<8; ++it){
    int r = it*16 + (t>>4);
    int k = (t&15)*8;
    int gr = rowBase + r;
    bf16x8 v = {0,0,0,0,0,0,0,0};
    if (gr < NNODES){
      f32x4 f0 = __builtin_nontemporal_load((const f32x4*)&x[(size_t)gr*128 + k]);
      f32x4 f1 = __builtin_nontemporal_load((const f32x4*)&x[(size_t)gr*128 + k + 4]);
      v[0]=(short)f2bf(f0[0]); v[1]=(short)f2bf(f0[1]); v[2]=(short)f2bf(f0[2]); v[3]=(short)f2bf(f0[3]);
      v[4]=(short)f2bf(f1[0]); v[5]=(short)f2bf(f1[1]); v[6]=(short)f2bf(f1[2]); v[7]=(short)f2bf(f1[3]);
    }
    *(bf16x8*)&As[r*128 + (k ^ ((r&7)<<3))] = v;
  }
  __syncthreads();

  const int wid = t>>6, lane = t&63;
  const int l16 = lane&15, kg = lane>>4;
  for (int net=0; net<NNETS; ++net){
    const short* Wt = w0t + (size_t)net*HF*HF;
    f32x4 acc[2][8];
    #pragma unroll
    for (int mt=0; mt<2; ++mt)
      #pragma unroll
      for (int nt=0; nt<8; ++nt){ acc[mt][nt][0]=0.f; acc[mt][nt][1]=0.f; acc[mt][nt][2]=0.f; acc[mt][nt][3]=0.f; }
    #pragma unroll
    for (int ks=0; ks<4; ++ks){
      int k0 = ks*32 + kg*8;
      bf16x8 a0, a1;
      { int r = wid*32 + l16;      a0 = *(const bf16x8*)&As[r*128 + (k0 ^ ((r&7)<<3))]; }
      { int r = wid*32 + 16 + l16; a1 = *(const bf16x8*)&As[r*128 + (k0 ^ ((r&7)<<3))]; }
      #pragma unroll
      for (int nt=0; nt<8; ++nt){
        bf16x8 b = *(const bf16x8*)&Wt[(size_t)(nt*16 + l16)*128 + k0];
        acc[0][nt] = __builtin_amdgcn_mfma_f32_16x16x32_bf16(a0, b, acc[0][nt], 0, 0, 0);
        acc[1][nt] = __builtin_amdgcn_mfma_f32_16x16x32_bf16(a1, b, acc[1][nt], 0, 0, 0);
      }
    }
    #pragma unroll
    for (int mt=0; mt<2; ++mt){
      #pragma unroll
      for (int nt=0; nt<8; ++nt){
        #pragma unroll
        for (int j=0; j<4; ++j){
          int row = rowBase + wid*32 + mt*16 + kg*4 + j;
          int col = nt*16 + l16;
          if (row < NNODES){
            float v = fmaxf(acc[mt][nt][j] + b0[net*HF + col], 0.f);
            short bv = (short)f2bf(v);
            h [IDX(row,net) + col] = bv;
            x0[IDX(row,net) + col] = bv;
          }
        }
      }
    }
  }
}

// ---------------- mid GEMM: t = 0.9*agg + 0.1*x0 (staged); h = relu((1-beta)*t + beta*(t @ cw)) ----------------
__global__ __launch_bounds__(256) void gemm_mid(
    const short* __restrict__ agg, const short* __restrict__ x0,
    const short* __restrict__ W, const float beta,
    short* __restrict__ outb)
{
  __shared__ short As[128*128];
  const int t = threadIdx.x;
  const int net = blockIdx.y;
  const int rowBase = blockIdx.x * 128;
  const short* Wt = W + (size_t)net*NLAYERS*HF*HF;

  #pragma unroll
  for (int it=0; it<8; ++it){
    int r = it*16 + (t>>4);
    int k = (t&15)*8;
    int gr = rowBase + r;
    bf16x8 v = {0,0,0,0,0,0,0,0};
    if (gr < NNODES){
      bf16x8 av = __builtin_nontemporal_load((const bf16x8*)&agg[IDX(gr,net) + k]);
      bf16x8 xv = *(const bf16x8*)&x0[IDX(gr,net) + k];
      #pragma unroll
      for (int j=0; j<8; ++j) v[j] = (short)f2bf(0.9f*bf2f(av[j]) + 0.1f*bf2f(xv[j]));
    }
    *(bf16x8*)&As[r*128 + (k ^ ((r&7)<<3))] = v;
  }
  __syncthreads();

  const int wid = t>>6, lane = t&63;
  const int l16 = lane&15, kg = lane>>4;
  f32x4 acc[2][8];
  #pragma unroll
  for (int mt=0; mt<2; ++mt)
    #pragma unroll
    for (int nt=0; nt<8; ++nt){ acc[mt][nt][0]=0.f; acc[mt][nt][1]=0.f; acc[mt][nt][2]=0.f; acc[mt][nt][3]=0.f; }

  #pragma unroll
  for (int ks=0; ks<4; ++ks){
    int k0 = ks*32 + kg*8;
    bf16x8 a0, a1;
    { int r = wid*32 + l16;      a0 = *(const bf16x8*)&As[r*128 + (k0 ^ ((r&7)<<3))]; }
    { int r = wid*32 + 16 + l16; a1 = *(const bf16x8*)&As[r*128 + (k0 ^ ((r&7)<<3))]; }
    #pragma unroll
    for (int nt=0; nt<8; ++nt){
      bf16x8 b = *(const bf16x8*)&Wt[(size_t)(nt*16 + l16)*128 + k0];
      acc[0][nt] = __builtin_amdgcn_mfma_f32_16x16x32_bf16(a0, b, acc[0][nt], 0, 0, 0);
      acc[1][nt] = __builtin_amdgcn_mfma_f32_16x16x32_bf16(a1, b, acc[1][nt], 0, 0, 0);
    }
  }

  #pragma unroll
  for (int mt=0; mt<2; ++mt){
    #pragma unroll
    for (int nt=0; nt<8; ++nt){
      #pragma unroll
      for (int j=0; j<4; ++j){
        int rl  = wid*32 + mt*16 + kg*4 + j;
        int row = rowBase + rl;
        int col = nt*16 + l16;
        if (row < NNODES){
          float av = bf2f(As[rl*128 + (col ^ ((rl&7)<<3))]);
          float v = fmaxf((1.f-beta)*av + beta*acc[mt][nt][j], 0.f);
          outb[IDX(row,net) + col] = (short)f2bf(v);
        }
      }
    }
  }
}

// ---------------- output GEMM: logits+log_softmax+ensemble mean, all 3 nets in-block ----------------
__global__ __launch_bounds__(256) void gemm_out(
    const short* __restrict__ h, const short* __restrict__ w1t, const float* __restrict__ b1,
    float* __restrict__ out)
{
  __shared__ short As[128*128];
  const int t = threadIdx.x;
  const int rowBase = blockIdx.x * 128;
  const int wid = t>>6, lane = t&63;
  const int l16 = lane&15, kg = lane>>4;

  f32x4 sum[2][7];
  #pragma unroll
  for (int mt=0; mt<2; ++mt)
    #pragma unroll
    for (int nt=0; nt<7; ++nt){ sum[mt][nt][0]=0.f; sum[mt][nt][1]=0.f; sum[mt][nt][2]=0.f; sum[mt][nt][3]=0.f; }

  for (int net=0; net<NNETS; ++net){
    __syncthreads();
    #pragma unroll
    for (int it=0; it<8; ++it){
      int r = it*16 + (t>>4);
      int k = (t&15)*8;
      int gr = rowBase + r;
      bf16x8 v = {0,0,0,0,0,0,0,0};
      if (gr < NNODES) v = *(const bf16x8*)&h[IDX(gr,net) + k];
      *(bf16x8*)&As[r*128 + (k ^ ((r&7)<<3))] = v;
    }
    __syncthreads();

    const short* Wt = w1t + (size_t)net*OUTF*HF;
    f32x4 acc[2][7];
    #pragma unroll
    for (int mt=0; mt<2; ++mt)
      #pragma unroll
      for (int nt=0; nt<7; ++nt){ acc[mt][nt][0]=0.f; acc[mt][nt][1]=0.f; acc[mt][nt][2]=0.f; acc[mt][nt][3]=0.f; }
    #pragma unroll
    for (int ks=0; ks<4; ++ks){
      int k0 = ks*32 + kg*8;
      bf16x8 a0, a1;
      { int r = wid*32 + l16;      a0 = *(const bf16x8*)&As[r*128 + (k0 ^ ((r&7)<<3))]; }
      { int r = wid*32 + 16 + l16; a1 = *(const bf16x8*)&As[r*128 + (k0 ^ ((r&7)<<3))]; }
      #pragma unroll
      for (int nt=0; nt<7; ++nt){
        bf16x8 b = *(const bf16x8*)&Wt[(size_t)(nt*16 + l16)*128 + k0];
        acc[0][nt] = __builtin_amdgcn_mfma_f32_16x16x32_bf16(a0, b, acc[0][nt], 0, 0, 0);
        acc[1][nt] = __builtin_amdgcn_mfma_f32_16x16x32_bf16(a1, b, acc[1][nt], 0, 0, 0);
      }
    }
    #pragma unroll
    for (int mt=0; mt<2; ++mt)
      #pragma unroll
      for (int nt=0; nt<7; ++nt){
        float b = b1[net*OUTF + nt*16 + l16];
        #pragma unroll
        for (int j=0; j<4; ++j) acc[mt][nt][j] += b;
      }
    #pragma unroll
    for (int mt=0; mt<2; ++mt){
      #pragma unroll
      for (int j=0; j<4; ++j){
        float m = -3.4e38f;
        #pragma unroll
        for (int nt=0; nt<7; ++nt) m = fmaxf(m, acc[mt][nt][j]);
        #pragma unroll
        for (int k=1; k<16; k<<=1) m = fmaxf(m, __shfl_xor(m, k));
        float e = 0.f;
        #pragma unroll
        for (int nt=0; nt<7; ++nt) e += expf(acc[mt][nt][j] - m);
        #pragma unroll
        for (int k=1; k<16; k<<=1) e += __shfl_xor(e, k);
        float lse = m + logf(e);
        #pragma unroll
        for (int nt=0; nt<7; ++nt) sum[mt][nt][j] += acc[mt][nt][j] - lse;
      }
    }
  }

  #pragma unroll
  for (int mt=0; mt<2; ++mt){
    #pragma unroll
    for (int nt=0; nt<7; ++nt){
      #pragma unroll
      for (int j=0; j<4; ++j){
        int row = rowBase + wid*32 + mt*16 + kg*4 + j;
        if (row < NNODES)
          __builtin_nontemporal_store(sum[mt][nt][j] * (1.f/3.f),
                                      &out[(size_t)row*OUTF + nt*16 + l16]);
      }
    }
  }
}

// ---------------- fused SpMM (all 3 nets, one CSR walk): agg = A @ h (raw, no combine) ----------------
// pure gather+reduce: csr nt-loads, agg nt-stores; h is the only cacheable stream
__global__ __launch_bounds__(256) void spmm3(
    const int* __restrict__ row_ptr, const u64* __restrict__ csr_pack,
    const short* __restrict__ h, short* __restrict__ aggb)
{
  int node = blockIdx.x*4 + (threadIdx.x>>6);
  int lane = threadIdx.x & 63;
  int q    = lane >> 4;
  int f8   = (lane & 15) * 8;
  int start = row_ptr[node], end = row_ptr[node+1];
  float acc[3][8] = {{0.f},{0.f},{0.f}};
  int e = start + q;
  for (; e + 4 < end; e += 8){
    u64 p0 = __builtin_nontemporal_load(&csr_pack[e]);
    u64 p1 = __builtin_nontemporal_load(&csr_pack[e+4]);
    int   s0 = (int)(unsigned)p0;
    float w0 = __builtin_bit_cast(float, (unsigned)(p0 >> 32));
    int   s1 = (int)(unsigned)p1;
    float w1 = __builtin_bit_cast(float, (unsigned)(p1 >> 32));
    const short* r0 = &h[(size_t)s0*(NNETS*128) + f8];
    const short* r1 = &h[(size_t)s1*(NNETS*128) + f8];
    bf16x8 a0 = *(const bf16x8*)(r0);
    bf16x8 a1 = *(const bf16x8*)(r0 + 128);
    bf16x8 a2 = *(const bf16x8*)(r0 + 256);
    bf16x8 c0 = *(const bf16x8*)(r1);
    bf16x8 c1 = *(const bf16x8*)(r1 + 128);
    bf16x8 c2 = *(const bf16x8*)(r1 + 256);
    #pragma unroll
    for (int j=0;j<8;++j){
      acc[0][j] += w0 * bf2f(a0[j]) + w1 * bf2f(c0[j]);
      acc[1][j] += w0 * bf2f(a1[j]) + w1 * bf2f(c1[j]);
      acc[2][j] += w0 * bf2f(a2[j]) + w1 * bf2f(c2[j]);
    }
  }
  if (e < end){
    u64 p0 = __builtin_nontemporal_load(&csr_pack[e]);
    int   s0 = (int)(unsigned)p0;
    float w0 = __builtin_bit_cast(float, (unsigned)(p0 >> 32));
    const short* r0 = &h[(size_t)s0*(NNETS*128) + f8];
    bf16x8 a0 = *(const bf16x8*)(r0);
    bf16x8 a1 = *(const bf16x8*)(r0 + 128);
    bf16x8 a2 = *(const bf16x8*)(r0 + 256);
    #pragma unroll
    for (int j=0;j<8;++j){
      acc[0][j] += w0 * bf2f(a0[j]);
      acc[1][j] += w0 * bf2f(a1[j]);
      acc[2][j] += w0 * bf2f(a2[j]);
    }
  }
  #pragma unroll
  for (int n=0;n<3;++n)
    #pragma unroll
    for (int j=0;j<8;++j){
      acc[n][j] += __shfl_xor(acc[n][j], 16);
      acc[n][j] += __shfl_xor(acc[n][j], 32);
    }
  if (q < 3){
    size_t base = (size_t)node*(NNETS*128) + q*128 + f8;
    u16x8 o;
    #pragma unroll
    for (int j=0;j<8;++j) o[j] = f2bf(acc[q][j]);
    __builtin_nontemporal_store(o, (u16x8*)&aggb[base]);
  }
}

extern "C" void kernel_launch(void* const* d_in, const int* in_sizes, int n_in,
                              void* d_out, int out_size, void* d_ws, size_t ws_size,
                              hipStream_t stream){
  const float* x  = (const float*)d_in[0];
  const int*   ei = (const int*)d_in[1];
  const float* ew = (const float*)d_in[2];
  const float* w0 = (const float*)d_in[3];
  const float* b0 = (const float*)d_in[4];
  const float* w1 = (const float*)d_in[5];
  const float* b1 = (const float*)d_in[6];
  const float* cw = (const float*)d_in[7];
  float* out = (float*)d_out;

  char* ws = (char*)d_ws;
  size_t o = 0;
  auto alloc = [&](size_t b){ size_t r = o; o += (b + 255) & ~(size_t)255; return r; };
  int*   flag     = (int*)(ws + alloc(256));
  int*   counts   = (int*)(ws + alloc((size_t)NNODES*4));
  int*   scanned  = (int*)(ws + alloc((size_t)NNODES*4));
  int*   cursor   = (int*)(ws + alloc((size_t)NNODES*4));
  int*   row_ptr  = (int*)(ws + alloc((size_t)(NNODES+1)*4));
  int*   partials = (int*)(ws + alloc(512*4));
  u64*   csr_pack = (u64*)(ws + alloc((size_t)NEDGES*8));
  short* w0t = (short*)(ws + alloc((size_t)NNETS*HF*HF*2));
  short* cwt = (short*)(ws + alloc((size_t)NNETS*NLAYERS*HF*HF*2));
  short* w1t = (short*)(ws + alloc((size_t)NNETS*OUTF*HF*2));
  short* hbuf= (short*)(ws + alloc((size_t)NNODES*NNETS*HF*2));
  short* x0b = (short*)(ws + alloc((size_t)NNODES*NNETS*HF*2));
  short* aggb= (short*)(ws + alloc((size_t)NNODES*NNETS*HF*2));
  (void)ws_size; (void)in_sizes; (void)n_in; (void)out_size;

  detect_fmt    <<<1,   64,  0, stream>>>((const u64*)ei, flag);
  zero_counts   <<<391, 256, 0, stream>>>(counts);
  hist_kernel   <<<6250,256, 0, stream>>>(ei, flag, counts);
  scan1         <<<391, 256, 0, stream>>>(counts, scanned, partials);
  scan2         <<<1,   512, 0, stream>>>(partials, 391);
  scan3         <<<391, 256, 0, stream>>>(scanned, partials, row_ptr, cursor);
  scatter_kernel<<<6250,256, 0, stream>>>(ei, ew, flag, cursor, csr_pack);

  prep_w<<<1128, 256, 0, stream>>>(w0, cw, w1, w0t, cwt, w1t);

  gemm_in<<<782, 256, 0, stream>>>(x, w0t, b0, hbuf, x0b);
  for (int l=0; l<NLAYERS; ++l){
    float beta = logf(0.5f/(float)(l+1) + 1.0f);
    spmm3<<<25000, 256, 0, stream>>>(row_ptr, csr_pack, hbuf, aggb);
    gemm_mid<<<dim3(782,3), 256, 0, stream>>>(aggb, x0b, cwt + (size_t)l*HF*HF, beta, hbuf);
  }
  gemm_out<<<782, 256, 0, stream>>>(hbuf, w1t, b1, out);
}

// Round 7
// 1487.659 us; speedup vs baseline: 1.0168x; 1.0168x over previous
//
#include <hip/hip_runtime.h>
#include <hip/hip_bf16.h>

#define NNODES 100000
#define NEDGES 1600000
#define INF_   128
#define HF     128
#define OUTF   112
#define NLAYERS 4
#define NNETS  3

typedef __attribute__((ext_vector_type(8))) short bf16x8;
typedef __attribute__((ext_vector_type(8))) unsigned short u16x8;
typedef __attribute__((ext_vector_type(4))) float f32x4;
typedef unsigned long long u64;

__device__ __forceinline__ float bf2f(short u){
  unsigned x = ((unsigned)(unsigned short)u) << 16;
  return __builtin_bit_cast(float, x);
}
__device__ __forceinline__ unsigned short f2bf(float f){
  unsigned u = __builtin_bit_cast(unsigned, f);
  u += 0x7fffu + ((u >> 16) & 1u);   // RNE
  return (unsigned short)(u >> 16);
}

// ---------------- int64-vs-int32 edge_index format probe ----------------
__global__ void detect_fmt(const u64* __restrict__ ei64, int* __restrict__ flag){
  u64 v = ei64[threadIdx.x];
  u64 b = __ballot((v >> 32) != 0ull);
  if (threadIdx.x == 0) flag[0] = (b == 0ull) ? 1 : 0;
}

__device__ __forceinline__ int load_dst(const int* ei, int is64, int e){
  return is64 ? ei[2*(NEDGES + e)] : ei[NEDGES + e];
}
__device__ __forceinline__ int load_src(const int* ei, int is64, int e){
  return is64 ? ei[2*e] : ei[e];
}

// ---------------- CSR build ----------------
__global__ void zero_counts(int* counts){
  int i = blockIdx.x*256 + threadIdx.x;
  if (i < NNODES) counts[i] = 0;
}

__global__ void hist_kernel(const int* __restrict__ ei, const int* __restrict__ flag, int* counts){
  int e = blockIdx.x*256 + threadIdx.x;
  if (e < NEDGES){
    int d = load_dst(ei, flag[0], e);
    if ((unsigned)d < NNODES) atomicAdd(&counts[d], 1);
  }
}

__global__ __launch_bounds__(256) void scan1(const int* __restrict__ counts,
                                             int* __restrict__ scanned,
                                             int* __restrict__ partials){
  __shared__ int s[256];
  int t = threadIdx.x, i = blockIdx.x*256 + t;
  int v = (i < NNODES) ? counts[i] : 0;
  s[t] = v; __syncthreads();
  for (int off=1; off<256; off<<=1){
    int a = (t >= off) ? s[t-off] : 0;
    __syncthreads();
    s[t] += a;
    __syncthreads();
  }
  if (i < NNODES) scanned[i] = s[t] - v;
  if (t == 255) partials[blockIdx.x] = s[255];
}

__global__ __launch_bounds__(512) void scan2(int* partials, int G){
  __shared__ int s[512];
  int t = threadIdx.x;
  int v = (t < G) ? partials[t] : 0;
  s[t] = v; __syncthreads();
  for (int off=1; off<512; off<<=1){
    int a = (t >= off) ? s[t-off] : 0;
    __syncthreads();
    s[t] += a;
    __syncthreads();
  }
  if (t < G) partials[t] = s[t] - v;
}

__global__ void scan3(const int* __restrict__ scanned, const int* __restrict__ partials,
                      int* __restrict__ row_ptr, int* __restrict__ cursor){
  int i = blockIdx.x*256 + threadIdx.x;
  if (i < NNODES){
    int v = scanned[i] + partials[i>>8];
    row_ptr[i] = v;
    cursor[i]  = v;
  } else if (i == NNODES){
    row_ptr[NNODES] = NEDGES;
  }
}

__global__ void scatter_kernel(const int* __restrict__ ei, const float* __restrict__ ew,
                               const int* __restrict__ flag,
                               int* cursor, u64* __restrict__ csr_pack){
  int e = blockIdx.x*256 + threadIdx.x;
  if (e < NEDGES){
    int is64 = flag[0];
    int s = load_src(ei, is64, e);
    int d = load_dst(ei, is64, e);
    float w = __builtin_nontemporal_load(&ew[e]);
    if ((unsigned)d < NNODES && (unsigned)s < NNODES){
      int pos = atomicAdd(&cursor[d], 1);
      if ((unsigned)pos < NEDGES){
        u64 pk = ((u64)__builtin_bit_cast(unsigned, w) << 32) | (unsigned)s;
        __builtin_nontemporal_store(pk, &csr_pack[pos]);
      }
    }
  }
}

// ---------------- weight prep (fp32 -> bf16, transposed to [C][K]) ----------------
__global__ void prep_w(const float* __restrict__ w0, const float* __restrict__ cw,
                       const float* __restrict__ w1,
                       short* __restrict__ w0t, short* __restrict__ cwt, short* __restrict__ w1t){
  int i = blockIdx.x*256 + threadIdx.x;
  const int n0 = NNETS*HF*HF;
  const int n1 = NNETS*NLAYERS*HF*HF;
  const int n2 = NNETS*OUTF*HF;
  if (i < n0){
    int net = i/(HF*HF), r = i%(HF*HF), c = r/HF, k = r%HF;
    w0t[i] = (short)f2bf(w0[(size_t)net*HF*HF + k*HF + c]);
  } else if (i < n0 + n1){
    int j = i - n0;
    int nl = j/(HF*HF), r = j%(HF*HF), c = r/HF, k = r%HF;
    cwt[j] = (short)f2bf(cw[(size_t)nl*HF*HF + k*HF + c]);
  } else if (i < n0 + n1 + n2){
    int j = i - n0 - n1;
    int net = j/(OUTF*HF), r = j%(OUTF*HF), c = r/HF, k = r%HF;
    w1t[j] = (short)f2bf(w1[(size_t)net*HF*OUTF + k*OUTF + c]);
  }
}

// All node-state buffers are interleaved: [node][net][128] bf16.
#define IDX(row,net) (((size_t)(row)*NNETS + (net))*128)

// ---------------- input GEMM: h0 = relu(x @ w0 + b0), x0 = h0, all 3 nets ----------------
__global__ __launch_bounds__(256) void gemm_in(
    const float* __restrict__ x, const short* __restrict__ w0t, const float* __restrict__ b0,
    short* __restrict__ h, short* __restrict__ x0)
{
  __shared__ short As[128*128];
  const int t = threadIdx.x;
  const int rowBase = blockIdx.x * 128;
  #pragma unroll
  for (int it=0; it<8; ++it){
    int r = it*16 + (t>>4);
    int k = (t&15)*8;
    int gr = rowBase + r;
    bf16x8 v = {0,0,0,0,0,0,0,0};
    if (gr < NNODES){
      f32x4 f0 = __builtin_nontemporal_load((const f32x4*)&x[(size_t)gr*128 + k]);
      f32x4 f1 = __builtin_nontemporal_load((const f32x4*)&x[(size_t)gr*128 + k + 4]);
      v[0]=(short)f2bf(f0[0]); v[1]=(short)f2bf(f0[1]); v[2]=(short)f2bf(f0[2]); v[3]=(short)f2bf(f0[3]);
      v[4]=(short)f2bf(f1[0]); v[5]=(short)f2bf(f1[1]); v[6]=(short)f2bf(f1[2]); v[7]=(short)f2bf(f1[3]);
    }
    *(bf16x8*)&As[r*128 + (k ^ ((r&7)<<3))] = v;
  }
  __syncthreads();

  const int wid = t>>6, lane = t&63;
  const int l16 = lane&15, kg = lane>>4;
  for (int net=0; net<NNETS; ++net){
    const short* Wt = w0t + (size_t)net*HF*HF;
    f32x4 acc[2][8];
    #pragma unroll
    for (int mt=0; mt<2; ++mt)
      #pragma unroll
      for (int nt=0; nt<8; ++nt){ acc[mt][nt][0]=0.f; acc[mt][nt][1]=0.f; acc[mt][nt][2]=0.f; acc[mt][nt][3]=0.f; }
    #pragma unroll
    for (int ks=0; ks<4; ++ks){
      int k0 = ks*32 + kg*8;
      bf16x8 a0, a1;
      { int r = wid*32 + l16;      a0 = *(const bf16x8*)&As[r*128 + (k0 ^ ((r&7)<<3))]; }
      { int r = wid*32 + 16 + l16; a1 = *(const bf16x8*)&As[r*128 + (k0 ^ ((r&7)<<3))]; }
      #pragma unroll
      for (int nt=0; nt<8; ++nt){
        bf16x8 b = *(const bf16x8*)&Wt[(size_t)(nt*16 + l16)*128 + k0];
        acc[0][nt] = __builtin_amdgcn_mfma_f32_16x16x32_bf16(a0, b, acc[0][nt], 0, 0, 0);
        acc[1][nt] = __builtin_amdgcn_mfma_f32_16x16x32_bf16(a1, b, acc[1][nt], 0, 0, 0);
      }
    }
    #pragma unroll
    for (int mt=0; mt<2; ++mt){
      #pragma unroll
      for (int nt=0; nt<8; ++nt){
        #pragma unroll
        for (int j=0; j<4; ++j){
          int row = rowBase + wid*32 + mt*16 + kg*4 + j;
          int col = nt*16 + l16;
          if (row < NNODES){
            float v = fmaxf(acc[mt][nt][j] + b0[net*HF + col], 0.f);
            short bv = (short)f2bf(v);
            h [IDX(row,net) + col] = bv;
            x0[IDX(row,net) + col] = bv;
          }
        }
      }
    }
  }
}

// ---------------- mid GEMM: t = 0.9*agg + 0.1*x0 (staged); h = relu((1-beta)*t + beta*(t @ cw)) ----------------
__global__ __launch_bounds__(256) void gemm_mid(
    const short* __restrict__ agg, const short* __restrict__ x0,
    const short* __restrict__ W, const float beta,
    short* __restrict__ outb)
{
  __shared__ short As[128*128];
  const int t = threadIdx.x;
  const int net = blockIdx.y;
  const int rowBase = blockIdx.x * 128;
  const short* Wt = W + (size_t)net*NLAYERS*HF*HF;

  #pragma unroll
  for (int it=0; it<8; ++it){
    int r = it*16 + (t>>4);
    int k = (t&15)*8;
    int gr = rowBase + r;
    bf16x8 v = {0,0,0,0,0,0,0,0};
    if (gr < NNODES){
      bf16x8 av = __builtin_nontemporal_load((const bf16x8*)&agg[IDX(gr,net) + k]);
      bf16x8 xv = *(const bf16x8*)&x0[IDX(gr,net) + k];
      #pragma unroll
      for (int j=0; j<8; ++j) v[j] = (short)f2bf(0.9f*bf2f(av[j]) + 0.1f*bf2f(xv[j]));
    }
    *(bf16x8*)&As[r*128 + (k ^ ((r&7)<<3))] = v;
  }
  __syncthreads();

  const int wid = t>>6, lane = t&63;
  const int l16 = lane&15, kg = lane>>4;
  f32x4 acc[2][8];
  #pragma unroll
  for (int mt=0; mt<2; ++mt)
    #pragma unroll
    for (int nt=0; nt<8; ++nt){ acc[mt][nt][0]=0.f; acc[mt][nt][1]=0.f; acc[mt][nt][2]=0.f; acc[mt][nt][3]=0.f; }

  #pragma unroll
  for (int ks=0; ks<4; ++ks){
    int k0 = ks*32 + kg*8;
    bf16x8 a0, a1;
    { int r = wid*32 + l16;      a0 = *(const bf16x8*)&As[r*128 + (k0 ^ ((r&7)<<3))]; }
    { int r = wid*32 + 16 + l16; a1 = *(const bf16x8*)&As[r*128 + (k0 ^ ((r&7)<<3))]; }
    #pragma unroll
    for (int nt=0; nt<8; ++nt){
      bf16x8 b = *(const bf16x8*)&Wt[(size_t)(nt*16 + l16)*128 + k0];
      acc[0][nt] = __builtin_amdgcn_mfma_f32_16x16x32_bf16(a0, b, acc[0][nt], 0, 0, 0);
      acc[1][nt] = __builtin_amdgcn_mfma_f32_16x16x32_bf16(a1, b, acc[1][nt], 0, 0, 0);
    }
  }

  #pragma unroll
  for (int mt=0; mt<2; ++mt){
    #pragma unroll
    for (int nt=0; nt<8; ++nt){
      #pragma unroll
      for (int j=0; j<4; ++j){
        int rl  = wid*32 + mt*16 + kg*4 + j;
        int row = rowBase + rl;
        int col = nt*16 + l16;
        if (row < NNODES){
          float av = bf2f(As[rl*128 + (col ^ ((rl&7)<<3))]);
          float v = fmaxf((1.f-beta)*av + beta*acc[mt][nt][j], 0.f);
          outb[IDX(row,net) + col] = (short)f2bf(v);
        }
      }
    }
  }
}

// ---------------- output GEMM: logits+log_softmax+ensemble mean, all 3 nets in-block ----------------
__global__ __launch_bounds__(256) void gemm_out(
    const short* __restrict__ h, const short* __restrict__ w1t, const float* __restrict__ b1,
    float* __restrict__ out)
{
  __shared__ short As[128*128];
  const int t = threadIdx.x;
  const int rowBase = blockIdx.x * 128;
  const int wid = t>>6, lane = t&63;
  const int l16 = lane&15, kg = lane>>4;

  f32x4 sum[2][7];
  #pragma unroll
  for (int mt=0; mt<2; ++mt)
    #pragma unroll
    for (int nt=0; nt<7; ++nt){ sum[mt][nt][0]=0.f; sum[mt][nt][1]=0.f; sum[mt][nt][2]=0.f; sum[mt][nt][3]=0.f; }

  for (int net=0; net<NNETS; ++net){
    __syncthreads();
    #pragma unroll
    for (int it=0; it<8; ++it){
      int r = it*16 + (t>>4);
      int k = (t&15)*8;
      int gr = rowBase + r;
      bf16x8 v = {0,0,0,0,0,0,0,0};
      if (gr < NNODES) v = *(const bf16x8*)&h[IDX(gr,net) + k];
      *(bf16x8*)&As[r*128 + (k ^ ((r&7)<<3))] = v;
    }
    __syncthreads();

    const short* Wt = w1t + (size_t)net*OUTF*HF;
    f32x4 acc[2][7];
    #pragma unroll
    for (int mt=0; mt<2; ++mt)
      #pragma unroll
      for (int nt=0; nt<7; ++nt){ acc[mt][nt][0]=0.f; acc[mt][nt][1]=0.f; acc[mt][nt][2]=0.f; acc[mt][nt][3]=0.f; }
    #pragma unroll
    for (int ks=0; ks<4; ++ks){
      int k0 = ks*32 + kg*8;
      bf16x8 a0, a1;
      { int r = wid*32 + l16;      a0 = *(const bf16x8*)&As[r*128 + (k0 ^ ((r&7)<<3))]; }
      { int r = wid*32 + 16 + l16; a1 = *(const bf16x8*)&As[r*128 + (k0 ^ ((r&7)<<3))]; }
      #pragma unroll
      for (int nt=0; nt<7; ++nt){
        bf16x8 b = *(const bf16x8*)&Wt[(size_t)(nt*16 + l16)*128 + k0];
        acc[0][nt] = __builtin_amdgcn_mfma_f32_16x16x32_bf16(a0, b, acc[0][nt], 0, 0, 0);
        acc[1][nt] = __builtin_amdgcn_mfma_f32_16x16x32_bf16(a1, b, acc[1][nt], 0, 0, 0);
      }
    }
    #pragma unroll
    for (int mt=0; mt<2; ++mt)
      #pragma unroll
      for (int nt=0; nt<7; ++nt){
        float b = b1[net*OUTF + nt*16 + l16];
        #pragma unroll
        for (int j=0; j<4; ++j) acc[mt][nt][j] += b;
      }
    #pragma unroll
    for (int mt=0; mt<2; ++mt){
      #pragma unroll
      for (int j=0; j<4; ++j){
        float m = -3.4e38f;
        #pragma unroll
        for (int nt=0; nt<7; ++nt) m = fmaxf(m, acc[mt][nt][j]);
        #pragma unroll
        for (int k=1; k<16; k<<=1) m = fmaxf(m, __shfl_xor(m, k));
        float e = 0.f;
        #pragma unroll
        for (int nt=0; nt<7; ++nt) e += expf(acc[mt][nt][j] - m);
        #pragma unroll
        for (int k=1; k<16; k<<=1) e += __shfl_xor(e, k);
        float lse = m + logf(e);
        #pragma unroll
        for (int nt=0; nt<7; ++nt) sum[mt][nt][j] += acc[mt][nt][j] - lse;
      }
    }
  }

  #pragma unroll
  for (int mt=0; mt<2; ++mt){
    #pragma unroll
    for (int nt=0; nt<7; ++nt){
      #pragma unroll
      for (int j=0; j<4; ++j){
        int row = rowBase + wid*32 + mt*16 + kg*4 + j;
        if (row < NNODES)
          __builtin_nontemporal_store(sum[mt][nt][j] * (1.f/3.f),
                                      &out[(size_t)row*OUTF + nt*16 + l16]);
      }
    }
  }
}

// ---------------- fused SpMM (all 3 nets): agg = A @ h ----------------
// one wave per node; quarter-wave per edge; unroll x4 -> up to 12 gathers in
// flight per quarter-wave (csr loads for all 4 edges issued before any FMA)
__global__ __launch_bounds__(256) void spmm3(
    const int* __restrict__ row_ptr, const u64* __restrict__ csr_pack,
    const short* __restrict__ h, short* __restrict__ aggb)
{
  int node = blockIdx.x*4 + (threadIdx.x>>6);
  int lane = threadIdx.x & 63;
  int q    = lane >> 4;
  int f8   = (lane & 15) * 8;
  int start = row_ptr[node], end = row_ptr[node+1];
  float acc[3][8] = {{0.f},{0.f},{0.f}};
  int e = start + q;
  for (; e + 12 < end; e += 16){
    u64 p0 = __builtin_nontemporal_load(&csr_pack[e]);
    u64 p1 = __builtin_nontemporal_load(&csr_pack[e+4]);
    u64 p2 = __builtin_nontemporal_load(&csr_pack[e+8]);
    u64 p3 = __builtin_nontemporal_load(&csr_pack[e+12]);
    const short* r0 = &h[(size_t)(unsigned)p0*(NNETS*128) + f8];
    const short* r1 = &h[(size_t)(unsigned)p1*(NNETS*128) + f8];
    const short* r2 = &h[(size_t)(unsigned)p2*(NNETS*128) + f8];
    const short* r3 = &h[(size_t)(unsigned)p3*(NNETS*128) + f8];
    float w0 = __builtin_bit_cast(float, (unsigned)(p0 >> 32));
    float w1 = __builtin_bit_cast(float, (unsigned)(p1 >> 32));
    float w2 = __builtin_bit_cast(float, (unsigned)(p2 >> 32));
    float w3 = __builtin_bit_cast(float, (unsigned)(p3 >> 32));
    bf16x8 a0 = *(const bf16x8*)(r0);
    bf16x8 a1 = *(const bf16x8*)(r0 + 128);
    bf16x8 a2 = *(const bf16x8*)(r0 + 256);
    bf16x8 b0 = *(const bf16x8*)(r1);
    bf16x8 b1 = *(const bf16x8*)(r1 + 128);
    bf16x8 b2 = *(const bf16x8*)(r1 + 256);
    bf16x8 c0 = *(const bf16x8*)(r2);
    bf16x8 c1 = *(const bf16x8*)(r2 + 128);
    bf16x8 c2 = *(const bf16x8*)(r2 + 256);
    bf16x8 d0 = *(const bf16x8*)(r3);
    bf16x8 d1 = *(const bf16x8*)(r3 + 128);
    bf16x8 d2 = *(const bf16x8*)(r3 + 256);
    #pragma unroll
    for (int j=0;j<8;++j){
      acc[0][j] += w0 * bf2f(a0[j]) + w1 * bf2f(b0[j]) + w2 * bf2f(c0[j]) + w3 * bf2f(d0[j]);
      acc[1][j] += w0 * bf2f(a1[j]) + w1 * bf2f(b1[j]) + w2 * bf2f(c1[j]) + w3 * bf2f(d1[j]);
      acc[2][j] += w0 * bf2f(a2[j]) + w1 * bf2f(b2[j]) + w2 * bf2f(c2[j]) + w3 * bf2f(d2[j]);
    }
  }
  for (; e < end; e += 4){
    u64 p0 = __builtin_nontemporal_load(&csr_pack[e]);
    int   s0 = (int)(unsigned)p0;
    float w0 = __builtin_bit_cast(float, (unsigned)(p0 >> 32));
    const short* r0 = &h[(size_t)s0*(NNETS*128) + f8];
    bf16x8 a0 = *(const bf16x8*)(r0);
    bf16x8 a1 = *(const bf16x8*)(r0 + 128);
    bf16x8 a2 = *(const bf16x8*)(r0 + 256);
    #pragma unroll
    for (int j=0;j<8;++j){
      acc[0][j] += w0 * bf2f(a0[j]);
      acc[1][j] += w0 * bf2f(a1[j]);
      acc[2][j] += w0 * bf2f(a2[j]);
    }
  }
  #pragma unroll
  for (int n=0;n<3;++n)
    #pragma unroll
    for (int j=0;j<8;++j){
      acc[n][j] += __shfl_xor(acc[n][j], 16);
      acc[n][j] += __shfl_xor(acc[n][j], 32);
    }
  if (q < 3){
    size_t base = (size_t)node*(NNETS*128) + q*128 + f8;
    u16x8 o;
    #pragma unroll
    for (int j=0;j<8;++j) o[j] = f2bf(acc[q][j]);
    __builtin_nontemporal_store(o, (u16x8*)&aggb[base]);
  }
}

extern "C" void kernel_launch(void* const* d_in, const int* in_sizes, int n_in,
                              void* d_out, int out_size, void* d_ws, size_t ws_size,
                              hipStream_t stream){
  const float* x  = (const float*)d_in[0];
  const int*   ei = (const int*)d_in[1];
  const float* ew = (const float*)d_in[2];
  const float* w0 = (const float*)d_in[3];
  const float* b0 = (const float*)d_in[4];
  const float* w1 = (const float*)d_in[5];
  const float* b1 = (const float*)d_in[6];
  const float* cw = (const float*)d_in[7];
  float* out = (float*)d_out;

  char* ws = (char*)d_ws;
  size_t o = 0;
  auto alloc = [&](size_t b){ size_t r = o; o += (b + 255) & ~(size_t)255; return r; };
  int*   flag     = (int*)(ws + alloc(256));
  int*   counts   = (int*)(ws + alloc((size_t)NNODES*4));
  int*   scanned  = (int*)(ws + alloc((size_t)NNODES*4));
  int*   cursor   = (int*)(ws + alloc((size_t)NNODES*4));
  int*   row_ptr  = (int*)(ws + alloc((size_t)(NNODES+1)*4));
  int*   partials = (int*)(ws + alloc(512*4));
  u64*   csr_pack = (u64*)(ws + alloc((size_t)NEDGES*8));
  short* w0t = (short*)(ws + alloc((size_t)NNETS*HF*HF*2));
  short* cwt = (short*)(ws + alloc((size_t)NNETS*NLAYERS*HF*HF*2));
  short* w1t = (short*)(ws + alloc((size_t)NNETS*OUTF*HF*2));
  short* hbuf= (short*)(ws + alloc((size_t)NNODES*NNETS*HF*2));
  short* x0b = (short*)(ws + alloc((size_t)NNODES*NNETS*HF*2));
  short* aggb= (short*)(ws + alloc((size_t)NNODES*NNETS*HF*2));
  (void)ws_size; (void)in_sizes; (void)n_in; (void)out_size;

  detect_fmt    <<<1,   64,  0, stream>>>((const u64*)ei, flag);
  zero_counts   <<<391, 256, 0, stream>>>(counts);
  hist_kernel   <<<6250,256, 0, stream>>>(ei, flag, counts);
  scan1         <<<391, 256, 0, stream>>>(counts, scanned, partials);
  scan2         <<<1,   512, 0, stream>>>(partials, 391);
  scan3         <<<391, 256, 0, stream>>>(scanned, partials, row_ptr, cursor);
  scatter_kernel<<<6250,256, 0, stream>>>(ei, ew, flag, cursor, csr_pack);

  prep_w<<<1128, 256, 0, stream>>>(w0, cw, w1, w0t, cwt, w1t);

  gemm_in<<<782, 256, 0, stream>>>(x, w0t, b0, hbuf, x0b);
  for (int l=0; l<NLAYERS; ++l){
    float beta = logf(0.5f/(float)(l+1) + 1.0f);
    spmm3<<<25000, 256, 0, stream>>>(row_ptr, csr_pack, hbuf, aggb);
    gemm_mid<<<dim3(782,3), 256, 0, stream>>>(aggb, x0b, cwt + (size_t)l*HF*HF, beta, hbuf);
  }
  gemm_out<<<782, 256, 0, stream>>>(hbuf, w1t, b1, out);
}